// Round 10
// baseline (404.794 us; speedup 1.0000x reference)
//
#include <hip/hip_runtime.h>

#define BLK  256
#define NBLK 512
#define PSB  1024
#define LGP  10
#define NBKM 128        // padded bucket count (actual nbk = 98)
#define GSUB 5          // sub-blocks per bucket (deg + agg phases)

struct MegaP {
    const float4* x; const int* row; const int* col;
    const float* W; const float* b; float* out;
    float4* sx; float* dis; unsigned short* blc; int* brow;
    unsigned int* bcntT; unsigned int* cpart; unsigned int* btot; unsigned int* boffs;
    unsigned int* degrep; float4* repB;
    unsigned int* barcnt; unsigned int* bargen;
    int n, E, nbk, NSTR2, CE, NPB8;
};

// device-wide barrier: generation counter + arrive count. All NBLK blocks are
// co-resident (16KB LDS, 256 thr -> capacity ~2048 blocks >> 512). The
// __threadfence() pair provides agent-scope L2 writeback/invalidate so plain
// global stores are cross-XCD visible after the barrier.
__device__ inline void gsync(unsigned int* cnt, unsigned int* gen) {
    __syncthreads();
    if (threadIdx.x == 0) {
        __threadfence();                        // release: wb L2
        unsigned int g = atomicAdd(gen, 0u);    // current generation (pre-arrival)
        unsigned int t = atomicAdd(cnt, 1u);
        if (t == NBLK - 1) {
            atomicExch(cnt, 0u);
            __threadfence();
            atomicAdd(gen, 1u);                 // open the gate
        } else {
            while (atomicAdd(gen, 0u) == g) { __builtin_amdgcn_s_sleep(2); }
        }
        __threadfence();                        // acquire: inv L2
    }
    __syncthreads();
}

__global__ __launch_bounds__(BLK, 2) void k_mega(MegaP P) {
    __shared__ unsigned int smem_u[4096];       // 16 KB, phase-aliased
    float*  smem_f = (float*)smem_u;
    float4* smem_4 = (float4*)smem_u;
    const int bid = blockIdx.x;
    const int tid = threadIdx.x;

    // ---- P1: bucket counts -> bcntT[bucket][block] ----
    for (int j = tid; j < P.nbk; j += BLK) smem_u[j] = 0u;
    __syncthreads();
    {
        int e0 = bid * P.CE, e1 = min(e0 + P.CE, P.E);
        for (int e = e0 + tid; e < e1; e += BLK)
            atomicAdd(&smem_u[((unsigned)P.col[e]) >> LGP], 1u);
    }
    __syncthreads();
    for (int j = tid; j < P.nbk; j += BLK) P.bcntT[j * NBLK + bid] = smem_u[j];
    gsync(P.barcnt, P.bargen);

    // ---- P2: per-bucket exclusive scan over NBLK block counts ----
    if (bid < P.nbk) {
        unsigned int v0 = P.bcntT[bid * NBLK + 2 * tid];
        unsigned int v1 = P.bcntT[bid * NBLK + 2 * tid + 1];
        smem_u[tid] = v0 + v1;
        __syncthreads();
        for (int off = 1; off < BLK; off <<= 1) {
            unsigned int u = (tid >= off) ? smem_u[tid - off] : 0u;
            __syncthreads();
            smem_u[tid] += u;
            __syncthreads();
        }
        unsigned int excl = smem_u[tid] - v0 - v1;
        P.cpart[bid * NBLK + 2 * tid]     = excl;
        P.cpart[bid * NBLK + 2 * tid + 1] = excl + v0;
        if (tid == BLK - 1) P.btot[bid] = smem_u[tid];
    }
    gsync(P.barcnt, P.bargen);

    // ---- P3: exclusive scan of bucket totals (block 0) ----
    if (bid == 0) {
        unsigned int v = 0;
        if (tid < NBKM) { v = (tid < P.nbk) ? P.btot[tid] : 0u; smem_u[tid] = v; }
        __syncthreads();
        for (int off = 1; off < NBKM; off <<= 1) {
            unsigned int u = 0;
            if (tid < NBKM && tid >= off) u = smem_u[tid - off];
            __syncthreads();
            if (tid < NBKM) smem_u[tid] += u;
            __syncthreads();
        }
        if (tid < P.nbk) P.boffs[tid] = smem_u[tid] - v;
    }
    gsync(P.barcnt, P.bargen);

    // ---- P4: fill — route (lc:u16, row) into bucket segments ----
    for (int j = tid; j < P.nbk; j += BLK)
        smem_u[j] = P.boffs[j] + P.cpart[j * NBLK + bid];
    __syncthreads();
    {
        int e0 = bid * P.CE, e1 = min(e0 + P.CE, P.E);
        for (int e = e0 + tid; e < e1; e += BLK) {
            int cv = P.col[e];
            unsigned int slot = atomicAdd(&smem_u[((unsigned)cv) >> LGP], 1u);
            P.blc[slot]  = (unsigned short)(cv & (PSB - 1));
            P.brow[slot] = P.row[e];
        }
    }
    gsync(P.barcnt, P.bargen);

    // ---- P5: per-bucket degree count, replica flush ----
    if (bid < P.nbk * GSUB) {
        const int p = bid / GSUB, g = bid % GSUB;
        for (int j = tid; j < PSB; j += BLK) smem_u[j] = 0u;
        __syncthreads();
        unsigned int s = P.boffs[p], len = P.btot[p];
        unsigned int ch = (len + GSUB - 1) / GSUB;
        unsigned int e0 = s + g * ch, e1 = min(e0 + ch, s + len);
        for (unsigned int e = e0 + tid; e < e1; e += BLK)
            atomicAdd(&smem_u[P.blc[e]], 1u);
        __syncthreads();
        unsigned int* dst = P.degrep + (size_t)g * P.NSTR2 + p * PSB;
        for (int j = tid; j < PSB; j += BLK) dst[j] = smem_u[j];
    }
    gsync(P.barcnt, P.bargen);

    // ---- P6: dis = rsqrt(1+deg), sx = dis * x ----
    {
        int i = bid * BLK + tid;                 // NBLK*BLK = 131072 >= n
        if (i < P.n) {
            unsigned int d = 0;
            #pragma unroll
            for (int g = 0; g < GSUB; ++g) d += P.degrep[(size_t)g * P.NSTR2 + i];
            float di = rsqrtf(1.0f + (float)d);
            float4 v = P.x[i];
            P.sx[i] = make_float4(di * v.x, di * v.y, di * v.z, di * v.w);
            P.dis[i] = di;
        }
    }
    gsync(P.barcnt, P.bargen);

    // ---- P7: bucket aggregation (LDS f32x4), replica flush ----
    if (bid < P.nbk * GSUB) {
        const int p = bid / GSUB, g = bid % GSUB;
        for (int j = tid; j < PSB; j += BLK) smem_4[j] = make_float4(0.f,0.f,0.f,0.f);
        __syncthreads();
        unsigned int s = P.boffs[p], len = P.btot[p];
        unsigned int ch = (len + GSUB - 1) / GSUB;
        unsigned int e0 = s + g * ch, e1 = min(e0 + ch, s + len);
        for (unsigned int e = e0 + tid; e < e1; e += BLK) {
            int lc = P.blc[e];
            float4 v = P.sx[P.brow[e]];          // L2-resident gather
            atomicAdd(&smem_f[lc * 4 + 0], v.x);
            atomicAdd(&smem_f[lc * 4 + 1], v.y);
            atomicAdd(&smem_f[lc * 4 + 2], v.z);
            atomicAdd(&smem_f[lc * 4 + 3], v.w);
        }
        __syncthreads();
        float4* dst = P.repB + (size_t)g * P.NSTR2 + p * PSB;
        for (int j = tid; j < PSB; j += BLK) dst[j] = smem_4[j];
    }
    gsync(P.barcnt, P.bargen);

    // ---- P8: reduce replicas + m-tile in LDS + GEMM-out ----
    {
        const int nb0 = bid * P.NPB8;
        if (tid < P.NPB8) {
            int i = nb0 + tid;
            if (i < P.n) {
                float4 a = P.sx[i];              // self term (dis_i * x_i)
                float ax = a.x, ay = a.y, az = a.z, aw = a.w;
                #pragma unroll
                for (int g = 0; g < GSUB; ++g) {
                    float4 v = P.repB[(size_t)g * P.NSTR2 + i];
                    ax += v.x; ay += v.y; az += v.z; aw += v.w;
                }
                float di = P.dis[i];
                smem_4[tid] = make_float4(di * ax, di * ay, di * az, di * aw);
            }
        }
        __syncthreads();
        const int c4 = (tid & 31) * 4;
        float4 w0 = *(const float4*)&P.W[0 * 128 + c4];
        float4 w1 = *(const float4*)&P.W[1 * 128 + c4];
        float4 w2 = *(const float4*)&P.W[2 * 128 + c4];
        float4 w3 = *(const float4*)&P.W[3 * 128 + c4];
        float4 bb = *(const float4*)&P.b[c4];
        for (int k = (tid >> 5); k < P.NPB8; k += 8) {
            int i = nb0 + k;
            if (i >= P.n) break;
            float4 mi = smem_4[k];
            float4 o;
            o.x = mi.x*w0.x + mi.y*w1.x + mi.z*w2.x + mi.w*w3.x + bb.x;
            o.y = mi.x*w0.y + mi.y*w1.y + mi.z*w2.y + mi.w*w3.y + bb.y;
            o.z = mi.x*w0.z + mi.y*w1.z + mi.z*w2.z + mi.w*w3.z + bb.z;
            o.w = mi.x*w0.w + mi.y*w1.w + mi.z*w2.w + mi.w*w3.w + bb.w;
            ((float4*)P.out)[(size_t)i * 32 + (tid & 31)] = o;
        }
    }
}

extern "C" void kernel_launch(void* const* d_in, const int* in_sizes, int n_in,
                              void* d_out, int out_size, void* d_ws, size_t ws_size,
                              hipStream_t stream) {
    const float* x  = (const float*)d_in[0];
    const int*   ei = (const int*)d_in[1];     // int64 in ref -> pushed as int32
    const float* W  = (const float*)d_in[2];
    const float* b  = (const float*)d_in[3];

    int n = in_sizes[0] / 4;       // 100000
    int E = in_sizes[1] / 2;       // 640000

    MegaP P;
    P.x   = (const float4*)x;
    P.row = ei;                    // sources
    P.col = ei + E;                // targets
    P.W = W; P.b = b; P.out = (float*)d_out;
    P.n = n; P.E = E;
    P.nbk   = (n + PSB - 1) >> LGP;            // 98
    P.NSTR2 = P.nbk * PSB;                     // 100352
    P.CE    = (E + NBLK - 1) / NBLK;           // 1250
    P.NPB8  = (n + NBLK - 1) / NBLK;           // 196

    // ws layout (4B words):
    //  sx[4n] | dis[n] | blc[(E+1)/2] | brow[E] | bcntT[NBKM*NBLK]
    //  | cpart[NBKM*NBLK] | btot[NBKM] | boffs[NBKM] | bar[2]
    //  | degrep[GSUB*NSTR2] | repB[GSUB*NSTR2*4]
    size_t o_sx    = 0;
    size_t o_dis   = o_sx + 4 * (size_t)n;
    size_t o_blc   = o_dis + (size_t)n;
    size_t o_brow  = o_blc + ((size_t)E + 1) / 2;
    size_t o_bcnt  = o_brow + (size_t)E;
    size_t o_cpart = o_bcnt + (size_t)NBKM * NBLK;
    size_t o_btot  = o_cpart + (size_t)NBKM * NBLK;
    size_t o_boffs = o_btot + NBKM;
    size_t o_bar   = o_boffs + NBKM;
    size_t o_deg   = o_bar + 2;
    size_t o_repB  = (o_deg + (size_t)GSUB * P.NSTR2 + 3) & ~(size_t)3;

    P.sx     = (float4*)((float*)d_ws + o_sx);
    P.dis    = (float*)d_ws + o_dis;
    P.blc    = (unsigned short*)((float*)d_ws + o_blc);
    P.brow   = (int*)d_ws + o_brow;
    P.bcntT  = (unsigned int*)d_ws + o_bcnt;
    P.cpart  = (unsigned int*)d_ws + o_cpart;
    P.btot   = (unsigned int*)d_ws + o_btot;
    P.boffs  = (unsigned int*)d_ws + o_boffs;
    P.barcnt = (unsigned int*)d_ws + o_bar;
    P.bargen = (unsigned int*)d_ws + o_bar + 1;
    P.degrep = (unsigned int*)d_ws + o_deg;
    P.repB   = (float4*)((float*)d_ws + o_repB);

    // reset barrier state each call (capture-safe, deterministic)
    hipMemsetAsync((void*)P.barcnt, 0, 2 * sizeof(unsigned int), stream);

    k_mega<<<NBLK, BLK, 0, stream>>>(P);
}